// Round 8
// baseline (107.844 us; speedup 1.0000x reference)
//
#include <hip/hip_runtime.h>

// LIF integrate-fire-reset scan over T.
// inputs: [B=32, T=2048, N=1024] f32; thresh: [N] f32; out: [B, T, N] f32.
//
// One LANE per (b, n) chain (512 waves = 2 waves/CU, the max the problem's
// chain-parallelism allows), but float4 memory ops via a single-wave LDS
// transpose:
//   load:  lane l reads x[b][4c + (l>>4)][n0 + 4*(l&15) .. +3]  (1 KB/wave/instr)
//   LDS tile [4 t][64 n] -> lane l reads its chain's 4 timesteps
//   compute 4 LIF steps in registers
//   LDS tile reversed -> lane l writes 4 (t, n-quad) outputs, float4 store.
//
// Why: scalar version was vmcnt-slot-capped (D=32 uses all 63 slots ->
// only 8 KB loads in flight per wave; need ~15-22 KB/CU to cover under-load
// HBM latency). float4 ops use 2 slots per 4 timesteps -> F=16 chunks
// (64 timesteps) in flight = 16 KB loads/wave = 32 KB/CU.
//
// Single-wave blocks: NO __syncthreads (its implicit vmcnt(0) drain would
// destroy the prefetch pipeline). LDS write->read visibility within one wave
// needs only s_waitcnt lgkmcnt(0) (+ sched_barrier(0), guide rule #18).

typedef float f32x4 __attribute__((ext_vector_type(4)));

constexpr int T_STEPS = 2048;
constexpr int N_COLS  = 1024;
constexpr int NCHUNK  = T_STEPS / 4;   // 512 chunks of 4 timesteps
constexpr int F       = 16;            // chunks in flight (64 timesteps ahead)

__global__ __launch_bounds__(64, 1)
void lif_scan_kernel(const float* __restrict__ x,
                     const float* __restrict__ thresh,
                     float* __restrict__ out)
{
    __shared__ float tileL[256];   // [4 t][64 n] load-side transpose tile
    __shared__ float tileS[256];   // [4 t][64 n] store-side transpose tile

    const int lane = threadIdx.x;            // 0..63, owns chain n0+lane
    const int b    = blockIdx.x >> 4;        // batch
    const int n0   = (blockIdx.x & 15) << 6; // 64-column slab

    const int tt = lane >> 4;          // chunk-local timestep this lane loads/stores
    const int nq = (lane & 15) << 2;   // n-quad this lane loads/stores

    const float thr = thresh[n0 + lane];

    // vector-op address: element (b, tt, n0+nq), advanced by 4*N_COLS per chunk
    const size_t vbase = (size_t)b * T_STEPS * N_COLS + (size_t)tt * N_COLS + n0 + nq;
    const float* __restrict__ pL = x   + vbase;
    float*       __restrict__ pS = out + vbase;

    const int wT = tt * 64 + nq;   // tile addr for the (t-major, n-quad) side

    f32x4 L[F];   // in-flight loaded chunks (fully static indexing -> registers)

    // prologue: prime F chunks
#pragma unroll
    for (int k = 0; k < F; ++k)
        L[k] = __builtin_nontemporal_load((const f32x4*)(pL + (size_t)k * 4 * N_COLS));

    float acc = 0.0f;

#define LIF_CHUNK(K, CBASE, PREFETCH)                                          \
    {                                                                          \
        const int c = (CBASE) + (K);                                           \
        /* load-transpose: deposit in-flight vector (compiler emits the */     \
        /* counted vmcnt wait for L[K] here, ~31 younger ops outstanding) */   \
        *(f32x4*)&tileL[wT] = L[K];                                            \
        if (PREFETCH)                                                          \
            L[K] = __builtin_nontemporal_load(                                 \
                (const f32x4*)(pL + (size_t)(c + F) * 4 * N_COLS));            \
        asm volatile("s_waitcnt lgkmcnt(0)" ::: "memory");                     \
        __builtin_amdgcn_sched_barrier(0);                                     \
        const float v0 = tileL[lane];                                          \
        const float v1 = tileL[lane + 64];                                     \
        const float v2 = tileL[lane + 128];                                    \
        const float v3 = tileL[lane + 192];                                    \
        float o0, o1, o2, o3;                                                  \
        acc += v0; o0 = (acc > thr) ? acc : 0.0f; acc -= o0;                   \
        acc += v1; o1 = (acc > thr) ? acc : 0.0f; acc -= o1;                   \
        acc += v2; o2 = (acc > thr) ? acc : 0.0f; acc -= o2;                   \
        acc += v3; o3 = (acc > thr) ? acc : 0.0f; acc -= o3;                   \
        /* store-transpose (prev chunk's tileS read already completed: its */  \
        /* global store waited on it before issuing; LDS pipe is in-order) */  \
        tileS[lane]       = o0;                                                \
        tileS[lane + 64]  = o1;                                                \
        tileS[lane + 128] = o2;                                                \
        tileS[lane + 192] = o3;                                                \
        asm volatile("s_waitcnt lgkmcnt(0)" ::: "memory");                     \
        __builtin_amdgcn_sched_barrier(0);                                     \
        const f32x4 S = *(const f32x4*)&tileS[wT];                             \
        __builtin_nontemporal_store(S, (f32x4*)(pS + (size_t)c * 4 * N_COLS)); \
    }

    // steady state: 31 outer iterations x 16 chunks, always prefetching c+F
    for (int cb = 0; cb < NCHUNK - F; cb += F) {
#pragma unroll
        for (int k = 0; k < F; ++k)
            LIF_CHUNK(k, cb, true)
    }
    // epilogue: drain the last F chunks (no prefetch)
#pragma unroll
    for (int k = 0; k < F; ++k)
        LIF_CHUNK(k, NCHUNK - F, false)

#undef LIF_CHUNK
}

extern "C" void kernel_launch(void* const* d_in, const int* in_sizes, int n_in,
                              void* d_out, int out_size, void* d_ws, size_t ws_size,
                              hipStream_t stream)
{
    const float* x      = (const float*)d_in[0];
    const float* thresh = (const float*)d_in[1];
    float*       out    = (float*)d_out;

    const int total = in_sizes[0] / T_STEPS;   // B * N chains = 32768
    (void)out_size; (void)d_ws; (void)ws_size; (void)n_in;

    const int block = 64;                      // one wave per block
    const int grid  = (total + block - 1) / block;   // 512 blocks

    hipLaunchKernelGGL(lif_scan_kernel, dim3(grid), dim3(block), 0, stream,
                       x, thresh, out);
}